// Round 4
// baseline (257.673 us; speedup 1.0000x reference)
//
#include <hip/hip_runtime.h>
#include <stdint.h>

#define IN_DIM  32768
#define OUT_DIM 32768
#define BATCH   1024
#define NT      1024
#define ITER    (OUT_DIM / 4 / NT)   // 8 float4-columns per thread
#define NBLK    256                   // 1 persistent block per CU
#define ROWS_PER_BLK (BATCH / NBLK)   // 4

__device__ __forceinline__ uint32_t f32_to_bf16_bits(float f) {
    uint32_t u = __builtin_bit_cast(uint32_t, f);
    return (u + 0x7FFFu + ((u >> 16) & 1u)) >> 16;   // RNE
}

// packed layout: low16 = (idx_a<<1) | flagA ; high16 = (idx_b<<1) | flagB
// idx<<1 is directly the LDS byte offset of the bf16 element.
__global__ void pack_meta(const int* __restrict__ idx_a,
                          const int* __restrict__ idx_b,
                          const float* __restrict__ logits,
                          uint32_t* __restrict__ packed) {
    int j = blockIdx.x * blockDim.x + threadIdx.x;
    if (j >= OUT_DIM) return;
    uint32_t ia = (((uint32_t)idx_a[j]) << 1) & 0xFFFFu;
    uint32_t ib = (((uint32_t)idx_b[j]) << 1) & 0xFFFFu;
    if (logits[2 * j + 0] > 0.0f) ia |= 1u;   // sigmoid(l)>0.5 <=> l>0
    if (logits[2 * j + 1] > 0.0f) ib |= 1u;
    packed[j] = ia | (ib << 16);
}

__device__ __forceinline__ float ldrow(const uint16_t* row, uint32_t byteoff) {
    uint16_t h = *(const uint16_t*)((const char*)row + byteoff);
    return __builtin_bit_cast(float, ((uint32_t)h) << 16);
}
__device__ __forceinline__ float sel(uint32_t flag, float v) {
    return flag ? 1.0f - v : v;
}

// Persistent: 1 block/CU, 4 rows each, double-buffered bf16 row cache.
// Per row-step: next-row global loads in flight over the gather+store phase.
__global__ __launch_bounds__(NT, 4) void logic_gather(
        const float* __restrict__ x,
        const uint32_t* __restrict__ packed,
        float* __restrict__ out) {
    __shared__ __align__(16) uint16_t rows[2][IN_DIM];   // 2 x 64 KiB
    const int t = threadIdx.x;

    // Metadata is row-invariant: load once, keep in registers for all 4 rows.
    const uint4* __restrict__ pk = (const uint4*)packed;
    uint4 p[ITER];
#pragma unroll
    for (int i = 0; i < ITER; ++i) p[i] = pk[i * NT + t];

    // Stage first row into buffer 0.
    int r = blockIdx.x;
    {
        const float4* __restrict__ xr = (const float4*)(x + (size_t)r * IN_DIM);
        uint2* __restrict__ dst = (uint2*)rows[0];
#pragma unroll
        for (int i = 0; i < 8; ++i) {
            int e4 = i * NT + t;
            float4 v = xr[e4];
            uint2 h;
            h.x = f32_to_bf16_bits(v.x) | (f32_to_bf16_bits(v.y) << 16);
            h.y = f32_to_bf16_bits(v.z) | (f32_to_bf16_bits(v.w) << 16);
            dst[e4] = h;
        }
    }
    __syncthreads();

#pragma unroll
    for (int k = 0; k < ROWS_PER_BLK; ++k) {
        const int cur = k & 1;
        const int rnext = r + NBLK;
        const bool have_next = (k + 1 < ROWS_PER_BLK);

        // (a) Issue next row's global loads FIRST — they stay in flight
        //     across the whole gather phase below.
        float4 nv[8];
        if (have_next) {
            const float4* __restrict__ xn = (const float4*)(x + (size_t)rnext * IN_DIM);
#pragma unroll
            for (int i = 0; i < 8; ++i) nv[i] = xn[i * NT + t];
        }

        // (b) Gather + compute + store current row (LDS + VALU + HBM writes).
        const uint16_t* __restrict__ rowbuf = rows[cur];
        float4* __restrict__ orow = (float4*)(out + (size_t)r * OUT_DIM);
#pragma unroll
        for (int i = 0; i < ITER; ++i) {
            const uint32_t w0 = p[i].x, w1 = p[i].y, w2 = p[i].z, w3 = p[i].w;
            float a0 = ldrow(rowbuf, w0 & 0xFFFEu), b0 = ldrow(rowbuf, (w0 >> 16) & 0xFFFEu);
            float a1 = ldrow(rowbuf, w1 & 0xFFFEu), b1 = ldrow(rowbuf, (w1 >> 16) & 0xFFFEu);
            float a2 = ldrow(rowbuf, w2 & 0xFFFEu), b2 = ldrow(rowbuf, (w2 >> 16) & 0xFFFEu);
            float a3 = ldrow(rowbuf, w3 & 0xFFFEu), b3 = ldrow(rowbuf, (w3 >> 16) & 0xFFFEu);
            float4 res;
            res.x = sel(w0 & 1u, a0) * sel(w0 & 0x10000u, b0);
            res.y = sel(w1 & 1u, a1) * sel(w1 & 0x10000u, b1);
            res.z = sel(w2 & 1u, a2) * sel(w2 & 0x10000u, b2);
            res.w = sel(w3 & 1u, a3) * sel(w3 & 0x10000u, b3);
            orow[i * NT + t] = res;
        }

        // (c) Convert + LDS-write next row into the other buffer.
        if (have_next) {
            uint2* __restrict__ dst = (uint2*)rows[cur ^ 1];
#pragma unroll
            for (int i = 0; i < 8; ++i) {
                int e4 = i * NT + t;
                uint2 h;
                h.x = f32_to_bf16_bits(nv[i].x) | (f32_to_bf16_bits(nv[i].y) << 16);
                h.y = f32_to_bf16_bits(nv[i].z) | (f32_to_bf16_bits(nv[i].w) << 16);
                dst[e4] = h;
            }
        }

        // One barrier per row-step: protects both buffers (prev reads done
        // before overwrite; writes done before next reads).
        __syncthreads();
        r = rnext;
    }
}

extern "C" void kernel_launch(void* const* d_in, const int* in_sizes, int n_in,
                              void* d_out, int out_size, void* d_ws, size_t ws_size,
                              hipStream_t stream) {
    const float* x      = (const float*)d_in[0];
    const float* logits = (const float*)d_in[1];
    const int*   idx_a  = (const int*)d_in[2];
    const int*   idx_b  = (const int*)d_in[3];
    uint32_t*    packed = (uint32_t*)d_ws;   // 128 KiB scratch
    float*       out    = (float*)d_out;

    hipLaunchKernelGGL(pack_meta, dim3(OUT_DIM / 256), dim3(256), 0, stream,
                       idx_a, idx_b, logits, packed);
    hipLaunchKernelGGL(logic_gather, dim3(NBLK), dim3(NT), 0, stream,
                       x, packed, out);
}